// Round 7
// baseline (188.858 us; speedup 1.0000x reference)
//
#include <hip/hip_runtime.h>

// out[b,o] = x[b,:] @ W_lin[:,o] + x[b] @ W_nl[o] @ x[b]
// Symmetric GEMM form (K=640 via 10 folded 8x8 block-pairs of W_nl+W_nl^T).
// 2-WAY K-split on 32-row chunks: waves (2t,2t+1) co-own 16-row tile t;
// wave half w01 runs steps t=10*w01..10*w01+9 (bW[10][2] = 80 VGPRs, loaded
// by the R2-verified formula). Each lane reads its whole 32-float x row as
// 8x ds_read_b128 from the XW32 xor-swizzled tile (R3-verified layout) and
// all windows/scalars are register selects (R6-verified). Halves the LDS
// pipe load vs R6: 32 row-reads / 2 partials / 1 barrier per 32 rows.
// Staging: ONE coalesced floatx4/thread per chunk, prefetched a full
// iteration ahead (R6 pattern). Linear: bf16(0.5*W_lin), exact pow2, each
// w01 half adds once. Reduce: R6's padded scalar scheme over 2 partials.

typedef __attribute__((ext_vector_type(8))) __bf16 bf16x8;
typedef __attribute__((ext_vector_type(4))) float floatx4;
typedef __attribute__((ext_vector_type(2))) float floatx2;

#define NB     524288
#define NCHUNK (NB / 32)    // 16384 chunks of 32 rows
#define GRID   768          // 3 blocks/CU; blocks 0..255 run 22 iters, rest 21
#define REDW   544          // 16 rows * 34 floats (pad 32->34)

// xor-swizzled x word (R3-verified): row r (0..31), element e (0..31)
__device__ __forceinline__ int XW32(int r, int e) {
    return r * 32 + ((((e >> 2) ^ (r & 7)) << 2) | (e & 3));
}

__device__ __forceinline__ bf16x8 pack8(floatx4 a, floatx4 b) {
    bf16x8 f;
    #pragma unroll
    for (int j = 0; j < 4; ++j) { f[j] = (__bf16)a[j]; f[j + 4] = (__bf16)b[j]; }
    return f;
}

__global__ __launch_bounds__(256, 3)
void nnode_kernel(const float* __restrict__ x, const float* __restrict__ Wlin,
                  const float* __restrict__ Wnl, float* __restrict__ out) {
    __shared__ __align__(16) float xs[2][1024];           // 8 KiB, swizzled 32x32
    __shared__ __align__(16) float red[2][2][2][REDW];    // 17 KiB [buf][tile][w01]

    const int tid  = threadIdx.x;
    const int wave = tid >> 6;
    const int lane = tid & 63;
    const int q    = lane >> 4;   // quad: A k-window / C row group
    const int col  = lane & 15;   // output column / A row
    const int tile = wave >> 1;   // 16-row tile (0,1) of the 32-row chunk
    const int w01  = wave & 1;    // K-split half

    // ---- B' fragments: this wave owns steps t = 10*w01 .. 10*w01+9 ----
    bf16x8 bW[10][2];
    #pragma unroll
    for (int kl = 0; kl < 10; ++kl) {
        const int t  = w01 * 10 + kl;
        const int p  = t >> 1, h = t & 1;
        const int pa = (p < 4) ? 0 : ((p < 7) ? 1 : ((p < 9) ? 2 : 3));
        const int pb = p - ((p < 4) ? 0 : ((p < 7) ? 3 : ((p < 9) ? 5 : 6)));
        const int i1 = 8 * pa + 4 * h + q;        // = 8a + u
        #pragma unroll
        for (int tt = 0; tt < 2; ++tt) {
            const float* base = Wnl + (size_t)(col + 16 * tt) * 1024;
            floatx4 v0 = *(const floatx4*)(base + i1 * 32 + 8 * pb);
            floatx4 v1 = *(const floatx4*)(base + i1 * 32 + 8 * pb + 4);
            if (pa != pb) {   // fold transposed block: += W_nl[o, 8b+v, 8a+u]
                #pragma unroll
                for (int j = 0; j < 4; ++j) {
                    v0[j] += base[(size_t)(8 * pb + j) * 32 + i1];
                    v1[j] += base[(size_t)(8 * pb + 4 + j) * 32 + i1];
                }
            }
            bW[kl][tt] = pack8(v0, v1);
        }
    }

    // ---- linear-part B fragments, half-scaled (both w01 halves add 1/2) ----
    bf16x8 bl0, bl1;
    #pragma unroll
    for (int j = 0; j < 8; ++j) {
        bl0[j] = (__bf16)(0.5f * Wlin[(q * 8 + j) * 32 + col]);
        bl1[j] = (__bf16)(0.5f * Wlin[(q * 8 + j) * 32 + col + 16]);
    }

    const bool q1 = (q & 1) != 0;
    const bool q2 = (q & 2) != 0;

    // staging map: thread -> (row tid>>3, granule tid&7), swizzled b128 word
    const int sword = (tid >> 3) * 32 + (((tid & 7) ^ ((tid >> 3) & 7)) << 2);
    const int xrow  = tile * 16 + col;    // this lane's x row within chunk
    // reduce map: thread -> (tile, row, col-quad)
    const int rT  = tid >> 7;
    const int rr  = (tid >> 3) & 15;
    const int rc4 = (tid & 7) * 4;

    const int n = 21 + ((blockIdx.x < (NCHUNK - 21 * GRID)) ? 1 : 0);

    // ---- prologue: stage chunk blockIdx.x into xs[0] ----
    {
        floatx4 v = *(const floatx4*)(x + (size_t)blockIdx.x * 1024 + tid * 4);
        *(floatx4*)&xs[0][sword] = v;
    }
    __syncthreads();

    int chunk = blockIdx.x;
    for (int k = 0; k < n; ++k, chunk += GRID) {
        const int cur = k & 1;

        // prefetch next chunk (coalesced 4KB/block); landed after compute
        floatx4 pre;
        if (k < n - 1)
            pre = *(const floatx4*)(x + (size_t)(chunk + GRID) * 1024 + tid * 4);

        // full row -> registers: 8x b128 (quad broadcast + 2-way banked)
        const float* xb = xs[cur];
        floatx4 X[8];
        #pragma unroll
        for (int j = 0; j < 8; ++j)
            X[j] = *(const floatx4*)&xb[XW32(xrow, 4 * j)];

        floatx4 acc0 = {0.f, 0.f, 0.f, 0.f};
        floatx4 acc1 = {0.f, 0.f, 0.f, 0.f};

        // scalar select X[i][q] via 3 cndmask (R6-verified)
        #define SELQ(V) (q2 ? (q1 ? (V)[3] : (V)[2]) : (q1 ? (V)[1] : (V)[0]))

        // linear part (half-scaled; window at q*8 via register selects)
        {
            floatx4 la0 = q2 ? (q1 ? X[6] : X[4]) : (q1 ? X[2] : X[0]);
            floatx4 la1 = q2 ? (q1 ? X[7] : X[5]) : (q1 ? X[3] : X[1]);
            bf16x8 af = pack8(la0, la1);
            acc0 = __builtin_amdgcn_mfma_f32_16x16x32_bf16(af, bl0, acc0, 0, 0, 0);
            acc1 = __builtin_amdgcn_mfma_f32_16x16x32_bf16(af, bl1, acc1, 0, 0, 0);
        }

        // one symmetric-packed k-step: af[j] = x[8a+4h+q] * x[8b+j]
        #define STEP(A, B, H, KL) {                                             \
            const float sc = SELQ(X[2 * (A) + (H)]);                            \
            floatx4 p0 = sc * X[2 * (B)];                                       \
            floatx4 p1 = sc * X[2 * (B) + 1];                                   \
            bf16x8 af = pack8(p0, p1);                                          \
            acc0 = __builtin_amdgcn_mfma_f32_16x16x32_bf16(af, bW[KL][0], acc0, 0, 0, 0); \
            acc1 = __builtin_amdgcn_mfma_f32_16x16x32_bf16(af, bW[KL][1], acc1, 0, 0, 0); }

        // wave-uniform branch; (a,b,h) literals match t = 10*w01 + kl
        if (w01 == 0) {
            STEP(0,0,0,0) STEP(0,0,1,1) STEP(0,1,0,2) STEP(0,1,1,3) STEP(0,2,0,4)
            STEP(0,2,1,5) STEP(0,3,0,6) STEP(0,3,1,7) STEP(1,1,0,8) STEP(1,1,1,9)
        } else {
            STEP(1,2,0,0) STEP(1,2,1,1) STEP(1,3,0,2) STEP(1,3,1,3) STEP(2,2,0,4)
            STEP(2,2,1,5) STEP(2,3,0,6) STEP(2,3,1,7) STEP(3,3,0,8) STEP(3,3,1,9)
        }
        #undef STEP
        #undef SELQ

        // ---- partials to LDS (R6 scheme: row = q*4+r2, col = col(+16)) ----
        {
            float* rp = &red[cur][tile][w01][0];
            #pragma unroll
            for (int r2 = 0; r2 < 4; ++r2) {
                rp[(q * 4 + r2) * 34 + col]      = acc0[r2];
                rp[(q * 4 + r2) * 34 + col + 16] = acc1[r2];
            }
        }
        // land the prefetched chunk into the other x buffer
        if (k < n - 1)
            *(floatx4*)&xs[cur ^ 1][sword] = pre;
        __syncthreads();

        // ---- reduce 2 partials; thread owns (tile rT, row rr, cols rc4..rc4+3) ----
        {
            const float* b0p = &red[cur][rT][0][rr * 34 + rc4];
            const float* b1p = &red[cur][rT][1][rr * 34 + rc4];
            floatx2 u0 = *(const floatx2*)(b0p);
            floatx2 u1 = *(const floatx2*)(b0p + 2);
            floatx2 v0 = *(const floatx2*)(b1p);
            floatx2 v1 = *(const floatx2*)(b1p + 2);
            floatx4 s = {u0.x + v0.x, u0.y + v0.y, u1.x + v1.x, u1.y + v1.y};
            *(floatx4*)(out + ((size_t)chunk * 32 + rT * 16 + rr) * 32 + rc4) = s;
        }
        // double-buffered xs/red; the single barrier orders reuse
    }
}

extern "C" void kernel_launch(void* const* d_in, const int* in_sizes, int n_in,
                              void* d_out, int out_size, void* d_ws, size_t ws_size,
                              hipStream_t stream) {
    const float* x    = (const float*)d_in[0];
    const float* Wlin = (const float*)d_in[1];
    const float* Wnl  = (const float*)d_in[2];
    float* out        = (float*)d_out;
    nnode_kernel<<<dim3(GRID), dim3(256), 0, stream>>>(x, Wlin, Wnl, out);
}

// Round 8
// 160.577 us; speedup vs baseline: 1.1761x; 1.1761x over previous
//
#include <hip/hip_runtime.h>

// out[b,o] = x[b,:] @ W_lin[:,o] + x[b] @ W_nl[o] @ x[b]
// Symmetric GEMM form (K=640 via 10 folded 8x8 block-pairs of W_nl+W_nl^T).
// 2-WAY K-split on 32-row chunks: waves (2t,2t+1) co-own 16-row tile t;
// wave half w01 runs steps t=10*w01..10*w01+9 (bW[10][2] = 80 VGPRs).
// R7 body verbatim (correctness-verified); this round changes ONLY the
// resource envelope: __launch_bounds__(256,2) kills the register spill that
// R7's (256,3) cap forced (FETCH/WRITE inflation +28MB = scratch traffic),
// and GRID=512 gives exactly 2 blocks/CU x 32 iterations, no tail.
// Each lane reads its whole 32-float x row as 8x ds_read_b128 from the XW32
// xor-swizzled tile; windows/scalars are register selects. Staging: ONE
// coalesced floatx4/thread per chunk, prefetched a full iteration ahead.
// Linear: bf16(0.5*W_lin), exact pow2, each w01 half adds once.

typedef __attribute__((ext_vector_type(8))) __bf16 bf16x8;
typedef __attribute__((ext_vector_type(4))) float floatx4;
typedef __attribute__((ext_vector_type(2))) float floatx2;

#define NB     524288
#define NCHUNK (NB / 32)    // 16384 chunks of 32 rows
#define GRID   512          // 2 blocks/CU, 32 iters/block, no tail
#define ITERS  (NCHUNK / GRID)
#define REDW   544          // 16 rows * 34 floats (pad 32->34)

// xor-swizzled x word (R3/R6-verified): row r (0..31), element e (0..31)
__device__ __forceinline__ int XW32(int r, int e) {
    return r * 32 + ((((e >> 2) ^ (r & 7)) << 2) | (e & 3));
}

__device__ __forceinline__ bf16x8 pack8(floatx4 a, floatx4 b) {
    bf16x8 f;
    #pragma unroll
    for (int j = 0; j < 4; ++j) { f[j] = (__bf16)a[j]; f[j + 4] = (__bf16)b[j]; }
    return f;
}

__global__ __launch_bounds__(256, 2)
void nnode_kernel(const float* __restrict__ x, const float* __restrict__ Wlin,
                  const float* __restrict__ Wnl, float* __restrict__ out) {
    __shared__ __align__(16) float xs[2][1024];           // 8 KiB, swizzled 32x32
    __shared__ __align__(16) float red[2][2][2][REDW];    // 17 KiB [buf][tile][w01]

    const int tid  = threadIdx.x;
    const int wave = tid >> 6;
    const int lane = tid & 63;
    const int q    = lane >> 4;   // quad: A k-window / C row group
    const int col  = lane & 15;   // output column / A row
    const int tile = wave >> 1;   // 16-row tile (0,1) of the 32-row chunk
    const int w01  = wave & 1;    // K-split half

    // ---- B' fragments: this wave owns steps t = 10*w01 .. 10*w01+9 ----
    bf16x8 bW[10][2];
    #pragma unroll
    for (int kl = 0; kl < 10; ++kl) {
        const int t  = w01 * 10 + kl;
        const int p  = t >> 1, h = t & 1;
        const int pa = (p < 4) ? 0 : ((p < 7) ? 1 : ((p < 9) ? 2 : 3));
        const int pb = p - ((p < 4) ? 0 : ((p < 7) ? 3 : ((p < 9) ? 5 : 6)));
        const int i1 = 8 * pa + 4 * h + q;        // = 8a + u
        #pragma unroll
        for (int tt = 0; tt < 2; ++tt) {
            const float* base = Wnl + (size_t)(col + 16 * tt) * 1024;
            floatx4 v0 = *(const floatx4*)(base + i1 * 32 + 8 * pb);
            floatx4 v1 = *(const floatx4*)(base + i1 * 32 + 8 * pb + 4);
            if (pa != pb) {   // fold transposed block: += W_nl[o, 8b+v, 8a+u]
                #pragma unroll
                for (int j = 0; j < 4; ++j) {
                    v0[j] += base[(size_t)(8 * pb + j) * 32 + i1];
                    v1[j] += base[(size_t)(8 * pb + 4 + j) * 32 + i1];
                }
            }
            bW[kl][tt] = pack8(v0, v1);
        }
    }

    // ---- linear-part B fragments, half-scaled (both w01 halves add 1/2) ----
    bf16x8 bl0, bl1;
    #pragma unroll
    for (int j = 0; j < 8; ++j) {
        bl0[j] = (__bf16)(0.5f * Wlin[(q * 8 + j) * 32 + col]);
        bl1[j] = (__bf16)(0.5f * Wlin[(q * 8 + j) * 32 + col + 16]);
    }

    const bool q1 = (q & 1) != 0;
    const bool q2 = (q & 2) != 0;

    // staging map: thread -> (row tid>>3, granule tid&7), swizzled b128 word
    const int sword = (tid >> 3) * 32 + (((tid & 7) ^ ((tid >> 3) & 7)) << 2);
    const int xrow  = tile * 16 + col;    // this lane's x row within chunk
    // reduce map: thread -> (tile, row, col-quad)
    const int rT  = tid >> 7;
    const int rr  = (tid >> 3) & 15;
    const int rc4 = (tid & 7) * 4;

    // ---- prologue: stage chunk blockIdx.x into xs[0] ----
    {
        floatx4 v = *(const floatx4*)(x + (size_t)blockIdx.x * 1024 + tid * 4);
        *(floatx4*)&xs[0][sword] = v;
    }
    __syncthreads();

    int chunk = blockIdx.x;
    for (int k = 0; k < ITERS; ++k, chunk += GRID) {
        const int cur = k & 1;

        // prefetch next chunk (coalesced 4KB/block); landed after compute
        floatx4 pre;
        if (k < ITERS - 1)
            pre = *(const floatx4*)(x + (size_t)(chunk + GRID) * 1024 + tid * 4);

        // full row -> registers: 8x b128 (quad broadcast + 2-way banked)
        const float* xb = xs[cur];
        floatx4 X[8];
        #pragma unroll
        for (int j = 0; j < 8; ++j)
            X[j] = *(const floatx4*)&xb[XW32(xrow, 4 * j)];

        floatx4 acc0 = {0.f, 0.f, 0.f, 0.f};
        floatx4 acc1 = {0.f, 0.f, 0.f, 0.f};

        // scalar select X[i][q] via 3 cndmask (R6-verified)
        #define SELQ(V) (q2 ? (q1 ? (V)[3] : (V)[2]) : (q1 ? (V)[1] : (V)[0]))

        // linear part (half-scaled; window at q*8 via register selects)
        {
            floatx4 la0 = q2 ? (q1 ? X[6] : X[4]) : (q1 ? X[2] : X[0]);
            floatx4 la1 = q2 ? (q1 ? X[7] : X[5]) : (q1 ? X[3] : X[1]);
            bf16x8 af = pack8(la0, la1);
            acc0 = __builtin_amdgcn_mfma_f32_16x16x32_bf16(af, bl0, acc0, 0, 0, 0);
            acc1 = __builtin_amdgcn_mfma_f32_16x16x32_bf16(af, bl1, acc1, 0, 0, 0);
        }

        // one symmetric-packed k-step: af[j] = x[8a+4h+q] * x[8b+j]
        #define STEP(A, B, H, KL) {                                             \
            const float sc = SELQ(X[2 * (A) + (H)]);                            \
            floatx4 p0 = sc * X[2 * (B)];                                       \
            floatx4 p1 = sc * X[2 * (B) + 1];                                   \
            bf16x8 af = pack8(p0, p1);                                          \
            acc0 = __builtin_amdgcn_mfma_f32_16x16x32_bf16(af, bW[KL][0], acc0, 0, 0, 0); \
            acc1 = __builtin_amdgcn_mfma_f32_16x16x32_bf16(af, bW[KL][1], acc1, 0, 0, 0); }

        // wave-uniform branch; (a,b,h) literals match t = 10*w01 + kl
        if (w01 == 0) {
            STEP(0,0,0,0) STEP(0,0,1,1) STEP(0,1,0,2) STEP(0,1,1,3) STEP(0,2,0,4)
            STEP(0,2,1,5) STEP(0,3,0,6) STEP(0,3,1,7) STEP(1,1,0,8) STEP(1,1,1,9)
        } else {
            STEP(1,2,0,0) STEP(1,2,1,1) STEP(1,3,0,2) STEP(1,3,1,3) STEP(2,2,0,4)
            STEP(2,2,1,5) STEP(2,3,0,6) STEP(2,3,1,7) STEP(3,3,0,8) STEP(3,3,1,9)
        }
        #undef STEP
        #undef SELQ

        // ---- partials to LDS (R6 scheme: row = q*4+r2, col = col(+16)) ----
        {
            float* rp = &red[cur][tile][w01][0];
            #pragma unroll
            for (int r2 = 0; r2 < 4; ++r2) {
                rp[(q * 4 + r2) * 34 + col]      = acc0[r2];
                rp[(q * 4 + r2) * 34 + col + 16] = acc1[r2];
            }
        }
        // land the prefetched chunk into the other x buffer
        if (k < ITERS - 1)
            *(floatx4*)&xs[cur ^ 1][sword] = pre;
        __syncthreads();

        // ---- reduce 2 partials; thread owns (tile rT, row rr, cols rc4..rc4+3) ----
        {
            const float* b0p = &red[cur][rT][0][rr * 34 + rc4];
            const float* b1p = &red[cur][rT][1][rr * 34 + rc4];
            floatx2 u0 = *(const floatx2*)(b0p);
            floatx2 u1 = *(const floatx2*)(b0p + 2);
            floatx2 v0 = *(const floatx2*)(b1p);
            floatx2 v1 = *(const floatx2*)(b1p + 2);
            floatx4 s = {u0.x + v0.x, u0.y + v0.y, u1.x + v1.x, u1.y + v1.y};
            *(floatx4*)(out + ((size_t)chunk * 32 + rT * 16 + rr) * 32 + rc4) = s;
        }
        // double-buffered xs/red; the single barrier orders reuse
    }
}

extern "C" void kernel_launch(void* const* d_in, const int* in_sizes, int n_in,
                              void* d_out, int out_size, void* d_ws, size_t ws_size,
                              hipStream_t stream) {
    const float* x    = (const float*)d_in[0];
    const float* Wlin = (const float*)d_in[1];
    const float* Wnl  = (const float*)d_in[2];
    float* out        = (float*)d_out;
    nnode_kernel<<<dim3(GRID), dim3(256), 0, stream>>>(x, Wlin, Wnl, out);
}